// Round 3
// baseline (153.184 us; speedup 1.0000x reference)
//
#include <hip/hip_runtime.h>

// MACE symmetric contraction, B=4096 nodes, C=256 channels, I=16.
//
// Per (b,c):  s[b,c] = sum_p x_p * t[b,p],
//   t[b,p] = sum_{k<256} Af[c,p,q,i]*x_q*x_i   (k=q*16+i)
//          + sum_q c2[c,p,q]*x_q (k=256+q)  +  c1[c,p] (k=272)
// => K=273 (pad 288=9*32) matmul on mfma_f32_16x16x32_bf16.
//
// R14 = BISECT round. R13 (triangular fold + 7-step repack + f32x2 packing)
// failed with absmax 2240 ~ 2x max|ref| (outputs uncorrelated). Three
// simultaneous changes -> cannot localize. This round:
//   contract_mfma = EXACT R12 text (verified, 152.9us).
//   precompute    = NEW staging (1 channel/block, 16KB LDS U3w) writing
//                   FOLDED coefficients in the OLD unit map:
//                   A[p, q*16+i] = U3w[q,i]+U3w[i,q] (q<i), U3w[q,q] (q=i),
//                   0 (q>i). Fold identity => result must equal R12 exactly
//                   (quadratic form contracted with symmetric x_q*x_i).
// If PASS: fold + staging validated; R15 = step repack as the only diff.
// If FAIL: fold/staging is the bug; 30-line diff to inspect.
//
// Kept from R12: dual accumulators, zero allocas (PromoteAlloca stripes
// private arrays into LDS otherwise), named-register x double-buffer,
// ~110 live-reg ceiling (R11: spills past that).
// Harness floor: ws-poison fill ~41us + d_in restore ~25us + misc => ~110us
// of dur_us is uncontrollable.

#define B_NODES 4096
#define C_CH    256
#define K3      23
#define K2      4

#define KSTEPS   9
#define KB_ELEMS (KSTEPS * 64 * 8)   // 4608 bf16 per channel
#define KB_U32   (KB_ELEMS / 2)      // 2304 u32 per channel

#define TILES_PER_WAVE 8             // 128 nodes per wave

typedef short    short8 __attribute__((ext_vector_type(8)));
typedef float    f32x4  __attribute__((ext_vector_type(4)));
typedef unsigned u32x4  __attribute__((ext_vector_type(4)));

// ws layout (bytes): [bfrag: C*4608*2][sT: C*B*4]
static constexpr size_t OFF_BF_BYTES = 0;
static constexpr size_t OFF_ST_BYTES = (size_t)C_CH * KB_ELEMS * 2;

__device__ inline unsigned short f2bf_rne(float f) {
  unsigned u = __builtin_bit_cast(unsigned, f);
  unsigned r = u + 0x7FFFu + ((u >> 16) & 1u);
  return (unsigned short)(r >> 16);
}

#define F2U(f) __builtin_bit_cast(unsigned, (f))
// pack two f32 (truncate-to-bf16 high halves) into one u32: [hi16(YH)|hi16(YL)]
#define PK2(YH, YL) __builtin_amdgcn_perm(F2U(YH), F2U(YL), 0x07060302u)

// ---------------------------------------------------------------------------
// Kernel 1: folded coeffs in OLD fragment order (lane&15 = p,
// k = s*32 + (lane>>4)*8 + j;  q = k>>4 = 2s+(g>>1), i = k&15 = (g&1)*8+j).
// One block per channel; U3w staged in 16KB LDS; fold applied in f32
// before bf16 quantization. Slots with q>i get exact 0.
// ---------------------------------------------------------------------------
__global__ __launch_bounds__(256) void precompute_bfrag(
    const float* __restrict__ U3, const float* __restrict__ U2,
    const float* __restrict__ U1, const float* __restrict__ w3,
    const float* __restrict__ w2, const float* __restrict__ w1,
    unsigned int* __restrict__ bfrag_u32) {
  const int c = blockIdx.x;
  const int t = threadIdx.x;

  __shared__ float su3w[4096];       // [p][q][i], this channel's U3w
  for (int l = t; l < 4096; l += 256) {
    float a = 0.f;
#pragma unroll
    for (int k3 = 0; k3 < K3; ++k3)
      a += U3[(size_t)l * K3 + k3] * w3[c * K3 + k3];   // w3: uniform scalar
    su3w[l] = a;
  }
  __syncthreads();

  const int lane = t >> 2;           // fragment lane
  const int jj   = (t & 3) * 2;      // 0,2,4,6
  const int p = lane & 15, g = lane >> 4;

  // steps 0..7: quadratic, old unit map, folded values.
#pragma unroll
  for (int s = 0; s < 8; ++s) {
    const int q = 2 * s + (g >> 1);
    float v0 = 0.f, v1 = 0.f;
#pragma unroll
    for (int e = 0; e < 2; ++e) {
      const int i = (g & 1) * 8 + jj + e;
      float a = 0.f;
      if (q < i)
        a = su3w[(p * 16 + q) * 16 + i] + su3w[(p * 16 + i) * 16 + q];
      else if (q == i)
        a = su3w[(p * 16 + q) * 16 + q];
      if (e == 0) v0 = a; else v1 = a;
    }
    bfrag_u32[(size_t)c * KB_U32 + s * 256 + t] =
        (unsigned)f2bf_rne(v0) | ((unsigned)f2bf_rne(v1) << 16);
  }

  // s == 8: linear rows (x_q), constant row (k==272), pad 0.  (R12 logic)
  {
    float v0 = 0.f, v1 = 0.f;
#pragma unroll
    for (int e = 0; e < 2; ++e) {
      const int k = 256 + g * 8 + jj + e;
      float a = 0.f;
      if (k < 272) {
        const int q = k - 256;
#pragma unroll
        for (int k2 = 0; k2 < K2; ++k2)
          a += U2[(size_t)(p * 16 + q) * K2 + k2] * w2[c * K2 + k2];
      } else if (k == 272) {
        a = U1[p] * w1[c];
      }
      if (e == 0) v0 = a; else v1 = a;
    }
    bfrag_u32[(size_t)c * KB_U32 + 8 * 256 + t] =
        (unsigned)f2bf_rne(v0) | ((unsigned)f2bf_rne(v1) << 16);
  }
}

// ---------------------------------------------------------------------------
// Kernel 2: wave-autonomous MFMA contraction, zero allocas.  (EXACT R12)
// Block = 256 thr (4 waves); wave w owns channel c0+w; 128 nodes/wave.
// Dual accumulators per tile: even steps -> acc, odd -> acc2 (chain 9 -> 5).
// ---------------------------------------------------------------------------

// One quadratic K-step: af rows = xq * xh[0..7], packed bf16.
#define QSTEP(BF, XQ, ACC)                                                     \
  __builtin_amdgcn_mfma_f32_16x16x32_bf16((BF),                                \
      __builtin_bit_cast(short8, (u32x4){                                      \
          PK2((XQ) * xh1, (XQ) * xh0), PK2((XQ) * xh3, (XQ) * xh2),            \
          PK2((XQ) * xh5, (XQ) * xh4), PK2((XQ) * xh7, (XQ) * xh6)}),          \
      (ACC), 0, 0, 0)

#define TILE_BODY(X0, X1, X2, X3, Tc)                                          \
  do {                                                                         \
    const float xh0 = ghi ? (X2).x : (X0).x;                                   \
    const float xh1 = ghi ? (X2).y : (X0).y;                                   \
    const float xh2 = ghi ? (X2).z : (X0).z;                                   \
    const float xh3 = ghi ? (X2).w : (X0).w;                                   \
    const float xh4 = ghi ? (X3).x : (X1).x;                                   \
    const float xh5 = ghi ? (X3).y : (X1).y;                                   \
    const float xh6 = ghi ? (X3).z : (X1).z;                                   \
    const float xh7 = ghi ? (X3).w : (X1).w;                                   \
    const float xq0 = gq ? (X0).y : (X0).x;                                    \
    const float xq1 = gq ? (X0).w : (X0).z;                                    \
    const float xq2 = gq ? (X1).y : (X1).x;                                    \
    const float xq3 = gq ? (X1).w : (X1).z;                                    \
    const float xq4 = gq ? (X2).y : (X2).x;                                    \
    const float xq5 = gq ? (X2).w : (X2).z;                                    \
    const float xq6 = gq ? (X3).y : (X3).x;                                    \
    const float xq7 = gq ? (X3).w : (X3).z;                                    \
    f32x4 acc  = (f32x4){0.f, 0.f, 0.f, 0.f};                                  \
    f32x4 acc2 = (f32x4){0.f, 0.f, 0.f, 0.f};                                  \
    acc  = QSTEP(bf0, xq0, acc);                                               \
    acc2 = QSTEP(bf1, xq1, acc2);                                              \
    acc  = QSTEP(bf2, xq2, acc);                                               \
    acc2 = QSTEP(bf3, xq3, acc2);                                              \
    acc  = QSTEP(bf4, xq4, acc);                                               \
    acc2 = QSTEP(bf5, xq5, acc2);                                              \
    acc  = QSTEP(bf6, xq6, acc);                                               \
    acc2 = QSTEP(bf7, xq7, acc2);                                              \
    {                                                                          \
      const float y0 = glin ? xh0 : cst;                                       \
      const float y1 = glin ? xh1 : 0.f;                                       \
      const float y2 = glin ? xh2 : 0.f;                                       \
      const float y3 = glin ? xh3 : 0.f;                                       \
      const float y4 = glin ? xh4 : 0.f;                                       \
      const float y5 = glin ? xh5 : 0.f;                                       \
      const float y6 = glin ? xh6 : 0.f;                                       \
      const float y7 = glin ? xh7 : 0.f;                                       \
      acc = __builtin_amdgcn_mfma_f32_16x16x32_bf16(bf8,                       \
          __builtin_bit_cast(short8, (u32x4){PK2(y1, y0), PK2(y3, y2),         \
                                             PK2(y5, y4), PK2(y7, y6)}),       \
          acc, 0, 0, 0);                                                       \
    }                                                                          \
    acc = acc + acc2;                                                          \
    const float4 xs = (g & 2) ? ((g & 1) ? (X3) : (X2))                        \
                              : ((g & 1) ? (X1) : (X0));                       \
    float v = acc[0] * xs.x + acc[1] * xs.y + acc[2] * xs.z + acc[3] * xs.w;   \
    v += __shfl_xor(v, 16);                                                    \
    v += __shfl_xor(v, 32);                                                    \
    if (g == 0) sTrow[(Tc) * 16 + n] = v;                                      \
  } while (0)

__global__ __launch_bounds__(256)
__attribute__((amdgpu_waves_per_eu(2, 4)))
void contract_mfma(
    const float* __restrict__ x, const short8* __restrict__ bfragv,
    float* __restrict__ sT) {
  const int c0  = blockIdx.x * 4;                    // channel group (fastest)
  const int nb0 = blockIdx.y * (TILES_PER_WAVE * 16);
  const int t   = threadIdx.x;
  const int w = t >> 6, lane = t & 63, n = lane & 15, g = lane >> 4;
  const int ch = c0 + w;

  // Coeff fragments: 9 coalesced dwordx4 into NAMED registers (36 VGPRs).
  const short8* bp = bfragv + (size_t)ch * (KSTEPS * 64);
  const short8 bf0 = bp[0 * 64 + lane];
  const short8 bf1 = bp[1 * 64 + lane];
  const short8 bf2 = bp[2 * 64 + lane];
  const short8 bf3 = bp[3 * 64 + lane];
  const short8 bf4 = bp[4 * 64 + lane];
  const short8 bf5 = bp[5 * 64 + lane];
  const short8 bf6 = bp[6 * 64 + lane];
  const short8 bf7 = bp[7 * 64 + lane];
  const short8 bf8 = bp[8 * 64 + lane];

  const bool  ghi  = (g & 1) != 0;        // i-half: i = (g&1)*8 + j
  const bool  gq   = ((g >> 1) & 1) != 0; // q = 2s + (g>>1)
  const bool  glin = (g < 2);             // step-8 linear rows live in g<2
  const float cst  = (g == 2) ? 1.0f : 0.0f;  // step-8 constant row
  float* sTrow = sT + (size_t)ch * B_NODES + nb0;

  // x address for lane's node in tile T: row (nb0+T*16+n), this wave's 64B.
  const float* xb = x + (size_t)(nb0 + n) * (C_CH * 16) + (size_t)ch * 16;
  const size_t tstride = (size_t)16 * C_CH * 16;     // 16 nodes

  // Named register double-buffer. No arrays, no address-of.
  float4 a0, a1, a2, a3, b0, b1, b2, b3;
  {
    const float4* p = (const float4*)xb;
    a0 = p[0]; a1 = p[1]; a2 = p[2]; a3 = p[3];
  }

#pragma unroll
  for (int TT = 0; TT < TILES_PER_WAVE / 2; ++TT) {
    {
      const float4* p = (const float4*)(xb + (size_t)(2 * TT + 1) * tstride);
      b0 = p[0]; b1 = p[1]; b2 = p[2]; b3 = p[3];
    }
    TILE_BODY(a0, a1, a2, a3, 2 * TT);
    if (TT + 1 < TILES_PER_WAVE / 2) {
      const float4* p = (const float4*)(xb + (size_t)(2 * TT + 2) * tstride);
      a0 = p[0]; a1 = p[1]; a2 = p[2]; a3 = p[3];
    }
    TILE_BODY(b0, b1, b2, b3, 2 * TT + 1);
  }
}

// ---------------------------------------------------------------------------
// Kernel 3: out[b,d] = (1/16) * sum_c sT[c,b] * W[c,d]  (fp32, 64x64 tiles)
// ---------------------------------------------------------------------------
__global__ __launch_bounds__(256) void linear_kernel(
    const float* __restrict__ sT, const float* __restrict__ W,
    float* __restrict__ out) {
  const int b0 = blockIdx.x * 64;
  const int d0 = blockIdx.y * 64;
  const int t  = threadIdx.x;
  const int tx = t & 15;
  const int ty = t >> 4;

  __shared__ float As[16][64];
  __shared__ float Bs[16][64];
  float acc[4][4] = {};

  for (int k0 = 0; k0 < C_CH; k0 += 16) {
    const int kk  = t >> 6;
    const int col = t & 63;
#pragma unroll
    for (int r = 0; r < 4; ++r) {
      As[kk + r * 4][col] = sT[(size_t)(k0 + kk + r * 4) * B_NODES + b0 + col];
      Bs[kk + r * 4][col] = W[(size_t)(k0 + kk + r * 4) * C_CH + d0 + col];
    }
    __syncthreads();
#pragma unroll
    for (int k = 0; k < 16; ++k) {
      float a[4], bv[4];
#pragma unroll
      for (int i = 0; i < 4; ++i) a[i] = As[k][ty * 4 + i];
#pragma unroll
      for (int j = 0; j < 4; ++j) bv[j] = Bs[k][tx * 4 + j];
#pragma unroll
      for (int i = 0; i < 4; ++i)
#pragma unroll
        for (int j = 0; j < 4; ++j) acc[i][j] += a[i] * bv[j];
    }
    __syncthreads();
  }

#pragma unroll
  for (int i = 0; i < 4; ++i) {
    float4 v = make_float4(acc[i][0] * 0.0625f, acc[i][1] * 0.0625f,
                           acc[i][2] * 0.0625f, acc[i][3] * 0.0625f);
    *(float4*)(out + (size_t)(b0 + ty * 4 + i) * C_CH + d0 + tx * 4) = v;
  }
}

extern "C" void kernel_launch(void* const* d_in, const int* in_sizes, int n_in,
                              void* d_out, int out_size, void* d_ws, size_t ws_size,
                              hipStream_t stream) {
  const float* x  = (const float*)d_in[0];
  const float* U3 = (const float*)d_in[1];
  const float* U2 = (const float*)d_in[2];
  const float* U1 = (const float*)d_in[3];
  const float* w3 = (const float*)d_in[4];
  const float* w2 = (const float*)d_in[5];
  const float* w1 = (const float*)d_in[6];
  const float* Wl = (const float*)d_in[7];

  unsigned int* bfrag = (unsigned int*)((char*)d_ws + OFF_BF_BYTES);
  float*        sT    = (float*)((char*)d_ws + OFF_ST_BYTES);
  float*        out   = (float*)d_out;

  precompute_bfrag<<<dim3(C_CH), dim3(256), 0, stream>>>(
      U3, U2, U1, w3, w2, w1, bfrag);
  contract_mfma<<<dim3(C_CH / 4, B_NODES / (TILES_PER_WAVE * 16)), dim3(256), 0, stream>>>(
      x, (const short8*)bfrag, sT);
  linear_kernel<<<dim3(B_NODES / 64, C_CH / 64), dim3(256), 0, stream>>>(sT, Wl, out);
}

// Round 4
// 151.334 us; speedup vs baseline: 1.0122x; 1.0122x over previous
//
#include <hip/hip_runtime.h>

// MACE symmetric contraction, B=4096 nodes, C=256 channels, I=16.
//
// Per (b,c):  s[b,c] = sum_p x_p * t[b,p],
//   t[b,p] = sum_{q<=i} Af[c,p,q,i]*x_q*x_i    (symmetric fold of U3w)
//          + sum_i c2[c,p,i]*x_i  +  c1[c,p]
// Af[p,q,i] = U3w[p,q,i]+U3w[p,i,q] (q<i), U3w[p,q,q] (q=i), 0 (q>i).
//
// R15 = R14 (fold in OLD 9-step layout, PASSED 153.2us) + step repack ONLY:
//   steps 0..3: q = 2s+(g>>1), i = (g&1)*8+j   [content identical to R14]
//   steps 4..5: q = 8+(s-4)*4+g, i = 8+j       [compacted: q>=8 has i>=8]
//   step  6   : linear rows (g<2), const (g==2,j==0), pad  [R14's s=8 text]
// => 7 MFMA K-steps (was 9). R13's f32x2 QSTEPV is EXCLUDED (prime suspect
// after R14 exonerated fold+staging; R12-consistency makes slot-map bugs
// permutation-invariant-impossible, so R13's failure was a code bug).
// Contract keeps R12's exact scalar-mul QSTEP arithmetic; the two new
// xq selects are explicit g== chains (3 cndmask each).
//
// Kept from R12: dual accumulators, zero allocas (PromoteAlloca stripes
// private arrays into LDS otherwise), named-register x double-buffer,
// ~110 live-reg ceiling (R11: spills past that).
// Harness floor: ws-poison fill ~41us + d_in restore ~25us + misc => ~110us
// of dur_us is uncontrollable.

#define B_NODES 4096
#define C_CH    256
#define K3      23
#define K2      4

#define KSTEPS   7
#define KB_ELEMS (KSTEPS * 64 * 8)   // 3584 bf16 per channel
#define KB_U32   (KB_ELEMS / 2)      // 1792 u32 per channel

#define TILES_PER_WAVE 8             // 128 nodes per wave

typedef short    short8 __attribute__((ext_vector_type(8)));
typedef float    f32x4  __attribute__((ext_vector_type(4)));
typedef unsigned u32x4  __attribute__((ext_vector_type(4)));

// ws layout (bytes): [bfrag: C*3584*2][sT: C*B*4]
static constexpr size_t OFF_BF_BYTES = 0;
static constexpr size_t OFF_ST_BYTES = (size_t)C_CH * KB_ELEMS * 2;

__device__ inline unsigned short f2bf_rne(float f) {
  unsigned u = __builtin_bit_cast(unsigned, f);
  unsigned r = u + 0x7FFFu + ((u >> 16) & 1u);
  return (unsigned short)(r >> 16);
}

#define F2U(f) __builtin_bit_cast(unsigned, (f))
// pack two f32 (truncate-to-bf16 high halves) into one u32: [hi16(YH)|hi16(YL)]
#define PK2(YH, YL) __builtin_amdgcn_perm(F2U(YH), F2U(YL), 0x07060302u)

// ---------------------------------------------------------------------------
// Kernel 1: folded coeffs, 7-step layout (lane&15 = p, slot j = 2*(t&3)+e).
// One block per channel; U3w staged in 16KB LDS; fold applied in f32
// before bf16 quantization. Triangle zeros (q>i) baked into coefficients.
// ---------------------------------------------------------------------------
__global__ __launch_bounds__(256) void precompute_bfrag(
    const float* __restrict__ U3, const float* __restrict__ U2,
    const float* __restrict__ U1, const float* __restrict__ w3,
    const float* __restrict__ w2, const float* __restrict__ w1,
    unsigned int* __restrict__ bfrag_u32) {
  const int c = blockIdx.x;
  const int t = threadIdx.x;

  __shared__ float su3w[4096];       // [p][q][i], this channel's U3w
  for (int l = t; l < 4096; l += 256) {
    float a = 0.f;
#pragma unroll
    for (int k3 = 0; k3 < K3; ++k3)
      a += U3[(size_t)l * K3 + k3] * w3[c * K3 + k3];   // w3: uniform scalar
    su3w[l] = a;
  }
  __syncthreads();

  const int lane = t >> 2;           // fragment lane
  const int jj   = (t & 3) * 2;      // 0,2,4,6
  const int p = lane & 15, g = lane >> 4;

  // steps 0..3: quadratic, low-q, old map. (content == R14 steps 0..3)
#pragma unroll
  for (int s = 0; s < 4; ++s) {
    const int q = 2 * s + (g >> 1);
    float v0 = 0.f, v1 = 0.f;
#pragma unroll
    for (int e = 0; e < 2; ++e) {
      const int i = (g & 1) * 8 + jj + e;
      float a = 0.f;
      if (q < i)
        a = su3w[(p * 16 + q) * 16 + i] + su3w[(p * 16 + i) * 16 + q];
      else if (q == i)
        a = su3w[(p * 16 + q) * 16 + q];
      if (e == 0) v0 = a; else v1 = a;
    }
    bfrag_u32[(size_t)c * KB_U32 + s * 256 + t] =
        (unsigned)f2bf_rne(v0) | ((unsigned)f2bf_rne(v1) << 16);
  }

  // steps 4..5: quadratic, high-q compacted: q = 8+(s-4)*4+g, i = 8+j.
#pragma unroll
  for (int s = 4; s < 6; ++s) {
    const int q = 8 + (s - 4) * 4 + g;
    float v0 = 0.f, v1 = 0.f;
#pragma unroll
    for (int e = 0; e < 2; ++e) {
      const int i = 8 + jj + e;
      float a = 0.f;
      if (q < i)
        a = su3w[(p * 16 + q) * 16 + i] + su3w[(p * 16 + i) * 16 + q];
      else if (q == i)
        a = su3w[(p * 16 + q) * 16 + q];
      if (e == 0) v0 = a; else v1 = a;
    }
    bfrag_u32[(size_t)c * KB_U32 + s * 256 + t] =
        (unsigned)f2bf_rne(v0) | ((unsigned)f2bf_rne(v1) << 16);
  }

  // step 6: linear rows (x_i), constant row, pad 0.  (R14's s=8 text)
  {
    float v0 = 0.f, v1 = 0.f;
#pragma unroll
    for (int e = 0; e < 2; ++e) {
      const int k = 256 + g * 8 + jj + e;
      float a = 0.f;
      if (k < 272) {
        const int q = k - 256;
#pragma unroll
        for (int k2 = 0; k2 < K2; ++k2)
          a += U2[(size_t)(p * 16 + q) * K2 + k2] * w2[c * K2 + k2];
      } else if (k == 272) {
        a = U1[p] * w1[c];
      }
      if (e == 0) v0 = a; else v1 = a;
    }
    bfrag_u32[(size_t)c * KB_U32 + 6 * 256 + t] =
        (unsigned)f2bf_rne(v0) | ((unsigned)f2bf_rne(v1) << 16);
  }
}

// ---------------------------------------------------------------------------
// Kernel 2: wave-autonomous MFMA contraction, zero allocas, 7 K-steps.
// Block = 256 thr (4 waves); wave w owns channel c0+w; 128 nodes/wave.
// Dual accumulators: acc <- bf0,bf2,bf4,bf6 ; acc2 <- bf1,bf3,bf5.
// ---------------------------------------------------------------------------

// R12's QSTEP with named H operands (identical arithmetic: scalar muls+PK2).
#define QSTEP8(BF, XQ, H0, H1, H2, H3, H4, H5, H6, H7, ACC)                    \
  __builtin_amdgcn_mfma_f32_16x16x32_bf16((BF),                                \
      __builtin_bit_cast(short8, (u32x4){                                      \
          PK2((XQ) * (H1), (XQ) * (H0)), PK2((XQ) * (H3), (XQ) * (H2)),        \
          PK2((XQ) * (H5), (XQ) * (H4)), PK2((XQ) * (H7), (XQ) * (H6))}),      \
      (ACC), 0, 0, 0)

#define TILE_BODY(X0, X1, X2, X3, Tc)                                          \
  do {                                                                         \
    const float xh0 = ghi ? (X2).x : (X0).x;                                   \
    const float xh1 = ghi ? (X2).y : (X0).y;                                   \
    const float xh2 = ghi ? (X2).z : (X0).z;                                   \
    const float xh3 = ghi ? (X2).w : (X0).w;                                   \
    const float xh4 = ghi ? (X3).x : (X1).x;                                   \
    const float xh5 = ghi ? (X3).y : (X1).y;                                   \
    const float xh6 = ghi ? (X3).z : (X1).z;                                   \
    const float xh7 = ghi ? (X3).w : (X1).w;                                   \
    const float xq0 = gq ? (X0).y : (X0).x;                                    \
    const float xq1 = gq ? (X0).w : (X0).z;                                    \
    const float xq2 = gq ? (X1).y : (X1).x;                                    \
    const float xq3 = gq ? (X1).w : (X1).z;                                    \
    const float xq4 = (g == 0) ? (X2).x                                        \
                   : (g == 1) ? (X2).y                                         \
                   : (g == 2) ? (X2).z : (X2).w;      /* x[8+g]  */            \
    const float xq5 = (g == 0) ? (X3).x                                        \
                   : (g == 1) ? (X3).y                                         \
                   : (g == 2) ? (X3).z : (X3).w;      /* x[12+g] */            \
    f32x4 acc  = (f32x4){0.f, 0.f, 0.f, 0.f};                                  \
    f32x4 acc2 = (f32x4){0.f, 0.f, 0.f, 0.f};                                  \
    acc  = QSTEP8(bf0, xq0, xh0, xh1, xh2, xh3, xh4, xh5, xh6, xh7, acc);      \
    acc2 = QSTEP8(bf1, xq1, xh0, xh1, xh2, xh3, xh4, xh5, xh6, xh7, acc2);     \
    acc  = QSTEP8(bf2, xq2, xh0, xh1, xh2, xh3, xh4, xh5, xh6, xh7, acc);      \
    acc2 = QSTEP8(bf3, xq3, xh0, xh1, xh2, xh3, xh4, xh5, xh6, xh7, acc2);     \
    acc  = QSTEP8(bf4, xq4, (X2).x, (X2).y, (X2).z, (X2).w,                    \
                  (X3).x, (X3).y, (X3).z, (X3).w, acc);                        \
    acc2 = QSTEP8(bf5, xq5, (X2).x, (X2).y, (X2).z, (X2).w,                    \
                  (X3).x, (X3).y, (X3).z, (X3).w, acc2);                       \
    {                                                                          \
      const float y0 = glin ? xh0 : cst;                                       \
      const float y1 = glin ? xh1 : 0.f;                                       \
      const float y2 = glin ? xh2 : 0.f;                                       \
      const float y3 = glin ? xh3 : 0.f;                                       \
      const float y4 = glin ? xh4 : 0.f;                                       \
      const float y5 = glin ? xh5 : 0.f;                                       \
      const float y6 = glin ? xh6 : 0.f;                                       \
      const float y7 = glin ? xh7 : 0.f;                                       \
      acc = __builtin_amdgcn_mfma_f32_16x16x32_bf16(bf6,                       \
          __builtin_bit_cast(short8, (u32x4){PK2(y1, y0), PK2(y3, y2),         \
                                             PK2(y5, y4), PK2(y7, y6)}),       \
          acc, 0, 0, 0);                                                       \
    }                                                                          \
    acc = acc + acc2;                                                          \
    const float4 xs = (g & 2) ? ((g & 1) ? (X3) : (X2))                        \
                              : ((g & 1) ? (X1) : (X0));                       \
    float v = acc[0] * xs.x + acc[1] * xs.y + acc[2] * xs.z + acc[3] * xs.w;   \
    v += __shfl_xor(v, 16);                                                    \
    v += __shfl_xor(v, 32);                                                    \
    if (g == 0) sTrow[(Tc) * 16 + n] = v;                                      \
  } while (0)

__global__ __launch_bounds__(256)
__attribute__((amdgpu_waves_per_eu(2, 4)))
void contract_mfma(
    const float* __restrict__ x, const short8* __restrict__ bfragv,
    float* __restrict__ sT) {
  const int c0  = blockIdx.x * 4;                    // channel group (fastest)
  const int nb0 = blockIdx.y * (TILES_PER_WAVE * 16);
  const int t   = threadIdx.x;
  const int w = t >> 6, lane = t & 63, n = lane & 15, g = lane >> 4;
  const int ch = c0 + w;

  // Coeff fragments: 7 coalesced dwordx4 into NAMED registers (28 VGPRs).
  const short8* bp = bfragv + (size_t)ch * (KSTEPS * 64);
  const short8 bf0 = bp[0 * 64 + lane];
  const short8 bf1 = bp[1 * 64 + lane];
  const short8 bf2 = bp[2 * 64 + lane];
  const short8 bf3 = bp[3 * 64 + lane];
  const short8 bf4 = bp[4 * 64 + lane];
  const short8 bf5 = bp[5 * 64 + lane];
  const short8 bf6 = bp[6 * 64 + lane];

  const bool  ghi  = (g & 1) != 0;        // i-half: i = (g&1)*8 + j
  const bool  gq   = ((g >> 1) & 1) != 0; // steps 0..3: q = 2s + (g>>1)
  const bool  glin = (g < 2);             // step-6 linear rows live in g<2
  const float cst  = (g == 2) ? 1.0f : 0.0f;  // step-6 constant row
  float* sTrow = sT + (size_t)ch * B_NODES + nb0;

  // x address for lane's node in tile T: row (nb0+T*16+n), this wave's 64B.
  const float* xb = x + (size_t)(nb0 + n) * (C_CH * 16) + (size_t)ch * 16;
  const size_t tstride = (size_t)16 * C_CH * 16;     // 16 nodes

  // Named register double-buffer. No arrays, no address-of.
  float4 a0, a1, a2, a3, b0, b1, b2, b3;
  {
    const float4* p = (const float4*)xb;
    a0 = p[0]; a1 = p[1]; a2 = p[2]; a3 = p[3];
  }

#pragma unroll
  for (int TT = 0; TT < TILES_PER_WAVE / 2; ++TT) {
    {
      const float4* p = (const float4*)(xb + (size_t)(2 * TT + 1) * tstride);
      b0 = p[0]; b1 = p[1]; b2 = p[2]; b3 = p[3];
    }
    TILE_BODY(a0, a1, a2, a3, 2 * TT);
    if (TT + 1 < TILES_PER_WAVE / 2) {
      const float4* p = (const float4*)(xb + (size_t)(2 * TT + 2) * tstride);
      a0 = p[0]; a1 = p[1]; a2 = p[2]; a3 = p[3];
    }
    TILE_BODY(b0, b1, b2, b3, 2 * TT + 1);
  }
}

// ---------------------------------------------------------------------------
// Kernel 3: out[b,d] = (1/16) * sum_c sT[c,b] * W[c,d]  (fp32, 64x64 tiles)
// ---------------------------------------------------------------------------
__global__ __launch_bounds__(256) void linear_kernel(
    const float* __restrict__ sT, const float* __restrict__ W,
    float* __restrict__ out) {
  const int b0 = blockIdx.x * 64;
  const int d0 = blockIdx.y * 64;
  const int t  = threadIdx.x;
  const int tx = t & 15;
  const int ty = t >> 4;

  __shared__ float As[16][64];
  __shared__ float Bs[16][64];
  float acc[4][4] = {};

  for (int k0 = 0; k0 < C_CH; k0 += 16) {
    const int kk  = t >> 6;
    const int col = t & 63;
#pragma unroll
    for (int r = 0; r < 4; ++r) {
      As[kk + r * 4][col] = sT[(size_t)(k0 + kk + r * 4) * B_NODES + b0 + col];
      Bs[kk + r * 4][col] = W[(size_t)(k0 + kk + r * 4) * C_CH + d0 + col];
    }
    __syncthreads();
#pragma unroll
    for (int k = 0; k < 16; ++k) {
      float a[4], bv[4];
#pragma unroll
      for (int i = 0; i < 4; ++i) a[i] = As[k][ty * 4 + i];
#pragma unroll
      for (int j = 0; j < 4; ++j) bv[j] = Bs[k][tx * 4 + j];
#pragma unroll
      for (int i = 0; i < 4; ++i)
#pragma unroll
        for (int j = 0; j < 4; ++j) acc[i][j] += a[i] * bv[j];
    }
    __syncthreads();
  }

#pragma unroll
  for (int i = 0; i < 4; ++i) {
    float4 v = make_float4(acc[i][0] * 0.0625f, acc[i][1] * 0.0625f,
                           acc[i][2] * 0.0625f, acc[i][3] * 0.0625f);
    *(float4*)(out + (size_t)(b0 + ty * 4 + i) * C_CH + d0 + tx * 4) = v;
  }
}

extern "C" void kernel_launch(void* const* d_in, const int* in_sizes, int n_in,
                              void* d_out, int out_size, void* d_ws, size_t ws_size,
                              hipStream_t stream) {
  const float* x  = (const float*)d_in[0];
  const float* U3 = (const float*)d_in[1];
  const float* U2 = (const float*)d_in[2];
  const float* U1 = (const float*)d_in[3];
  const float* w3 = (const float*)d_in[4];
  const float* w2 = (const float*)d_in[5];
  const float* w1 = (const float*)d_in[6];
  const float* Wl = (const float*)d_in[7];

  unsigned int* bfrag = (unsigned int*)((char*)d_ws + OFF_BF_BYTES);
  float*        sT    = (float*)((char*)d_ws + OFF_ST_BYTES);
  float*        out   = (float*)d_out;

  precompute_bfrag<<<dim3(C_CH), dim3(256), 0, stream>>>(
      U3, U2, U1, w3, w2, w1, bfrag);
  contract_mfma<<<dim3(C_CH / 4, B_NODES / (TILES_PER_WAVE * 16)), dim3(256), 0, stream>>>(
      x, (const short8*)bfrag, sT);
  linear_kernel<<<dim3(B_NODES / 64, C_CH / 64), dim3(256), 0, stream>>>(sT, Wl, out);
}

// Round 6
// 138.602 us; speedup vs baseline: 1.1052x; 1.0919x over previous
//
#include <hip/hip_runtime.h>

// MACE symmetric contraction, B=4096 nodes, C=256 channels, I=16.
//
// Per (b,c):  s[b,c] = sum_p x_p * t[b,p],
//   t[b,p] = sum_{q<=i} Af[c,p,q,i]*x_q*x_i    (symmetric fold of U3w)
//          + sum_i c2[c,p,i]*x_i  +  c1[c,p]
// Af[p,q,i] = U3w[p,q,i]+U3w[p,i,q] (q<i), U3w[p,q,q] (q=i), 0 (q>i).
// 7 MFMA K-steps of 32 (R15, PASSED 151.3us).
//
// R16 = R15 + LDS-staged x pipeline (contract only; kernels 1,3 untouched).
// R15 post-mortem: step-count cut gave only -1.9us => contract (~29us) has
// ~20us step-independent part. VALU floor ~7us, x-HBM floor ~11us => the
// contract is x-LOAD LATENCY-bound: reg double-buffer covers 1 tile (~270cy)
// vs ~600-900cy mem latency at 4 waves/SIMD. Fix: global_load_lds width=16
// (one instr stages a whole 1KB tile: 64 lanes x 16B), all 8 tiles issued
// up-front, counted s_waitcnt vmcnt(7-T) per tile (never 0) + sched_barrier
// (rule 18). Kills 4x redundant per-g x loads, frees 32 VGPRs.
// LDS read swizzle (rule 21, both-sides): chunk ^= (node>>1)&3 pre-applied
// to the GLOBAL source address (LDS dest stays linear: wave-uniform base +
// lane*16), inverse applied on ds_read => 2-way bank conflicts (free) +
// 4-lane same-addr broadcast. Stores deferred to epilogue so vmcnt counts
// only the 7 bfrag loads + 8 stage ops.
// (R17 resubmit: R16 bench was an infra 'container failed twice'; source
// re-audited for hang risk — vmcnt counting is interleave-proof, no OOB,
// wave-uniform LDS dest — byte-identical resubmission.)
//
// Kept: dual accumulators, zero allocas, ~110 live-reg ceiling (R11 lesson).
// Harness floor: ws-poison fill ~41us + d_in restore ~25us + misc => ~110us
// of dur_us is uncontrollable.

#define B_NODES 4096
#define C_CH    256
#define K3      23
#define K2      4

#define KSTEPS   7
#define KB_ELEMS (KSTEPS * 64 * 8)   // 3584 bf16 per channel
#define KB_U32   (KB_ELEMS / 2)      // 1792 u32 per channel

#define TILES_PER_WAVE 8             // 128 nodes per wave

typedef short    short8 __attribute__((ext_vector_type(8)));
typedef float    f32x4  __attribute__((ext_vector_type(4)));
typedef unsigned u32x4  __attribute__((ext_vector_type(4)));

// ws layout (bytes): [bfrag: C*3584*2][sT: C*B*4]
static constexpr size_t OFF_BF_BYTES = 0;
static constexpr size_t OFF_ST_BYTES = (size_t)C_CH * KB_ELEMS * 2;

__device__ inline unsigned short f2bf_rne(float f) {
  unsigned u = __builtin_bit_cast(unsigned, f);
  unsigned r = u + 0x7FFFu + ((u >> 16) & 1u);
  return (unsigned short)(r >> 16);
}

#define F2U(f) __builtin_bit_cast(unsigned, (f))
// pack two f32 (truncate-to-bf16 high halves) into one u32: [hi16(YH)|hi16(YL)]
#define PK2(YH, YL) __builtin_amdgcn_perm(F2U(YH), F2U(YL), 0x07060302u)

// async global->LDS, 16B/lane; LDS dest = wave-uniform base + lane*16.
__device__ __forceinline__ void stage16(const float* g, float* l) {
  __builtin_amdgcn_global_load_lds(
      (const __attribute__((address_space(1))) unsigned int*)g,
      (__attribute__((address_space(3))) unsigned int*)l, 16, 0, 0);
}

// ---------------------------------------------------------------------------
// Kernel 1: folded coeffs, 7-step layout (lane&15 = p, slot j = 2*(t&3)+e).
// One block per channel; U3w staged in 16KB LDS; fold applied in f32
// before bf16 quantization. Triangle zeros (q>i) baked into coefficients.
// (UNCHANGED from R15.)
// ---------------------------------------------------------------------------
__global__ __launch_bounds__(256) void precompute_bfrag(
    const float* __restrict__ U3, const float* __restrict__ U2,
    const float* __restrict__ U1, const float* __restrict__ w3,
    const float* __restrict__ w2, const float* __restrict__ w1,
    unsigned int* __restrict__ bfrag_u32) {
  const int c = blockIdx.x;
  const int t = threadIdx.x;

  __shared__ float su3w[4096];       // [p][q][i], this channel's U3w
  for (int l = t; l < 4096; l += 256) {
    float a = 0.f;
#pragma unroll
    for (int k3 = 0; k3 < K3; ++k3)
      a += U3[(size_t)l * K3 + k3] * w3[c * K3 + k3];   // w3: uniform scalar
    su3w[l] = a;
  }
  __syncthreads();

  const int lane = t >> 2;           // fragment lane
  const int jj   = (t & 3) * 2;      // 0,2,4,6
  const int p = lane & 15, g = lane >> 4;

  // steps 0..3: quadratic, low-q, old map.
#pragma unroll
  for (int s = 0; s < 4; ++s) {
    const int q = 2 * s + (g >> 1);
    float v0 = 0.f, v1 = 0.f;
#pragma unroll
    for (int e = 0; e < 2; ++e) {
      const int i = (g & 1) * 8 + jj + e;
      float a = 0.f;
      if (q < i)
        a = su3w[(p * 16 + q) * 16 + i] + su3w[(p * 16 + i) * 16 + q];
      else if (q == i)
        a = su3w[(p * 16 + q) * 16 + q];
      if (e == 0) v0 = a; else v1 = a;
    }
    bfrag_u32[(size_t)c * KB_U32 + s * 256 + t] =
        (unsigned)f2bf_rne(v0) | ((unsigned)f2bf_rne(v1) << 16);
  }

  // steps 4..5: quadratic, high-q compacted: q = 8+(s-4)*4+g, i = 8+j.
#pragma unroll
  for (int s = 4; s < 6; ++s) {
    const int q = 8 + (s - 4) * 4 + g;
    float v0 = 0.f, v1 = 0.f;
#pragma unroll
    for (int e = 0; e < 2; ++e) {
      const int i = 8 + jj + e;
      float a = 0.f;
      if (q < i)
        a = su3w[(p * 16 + q) * 16 + i] + su3w[(p * 16 + i) * 16 + q];
      else if (q == i)
        a = su3w[(p * 16 + q) * 16 + q];
      if (e == 0) v0 = a; else v1 = a;
    }
    bfrag_u32[(size_t)c * KB_U32 + s * 256 + t] =
        (unsigned)f2bf_rne(v0) | ((unsigned)f2bf_rne(v1) << 16);
  }

  // step 6: linear rows (x_i), constant row, pad 0.
  {
    float v0 = 0.f, v1 = 0.f;
#pragma unroll
    for (int e = 0; e < 2; ++e) {
      const int k = 256 + g * 8 + jj + e;
      float a = 0.f;
      if (k < 272) {
        const int q = k - 256;
#pragma unroll
        for (int k2 = 0; k2 < K2; ++k2)
          a += U2[(size_t)(p * 16 + q) * K2 + k2] * w2[c * K2 + k2];
      } else if (k == 272) {
        a = U1[p] * w1[c];
      }
      if (e == 0) v0 = a; else v1 = a;
    }
    bfrag_u32[(size_t)c * KB_U32 + 6 * 256 + t] =
        (unsigned)f2bf_rne(v0) | ((unsigned)f2bf_rne(v1) << 16);
  }
}

// ---------------------------------------------------------------------------
// Kernel 2: wave-autonomous MFMA contraction, 7 K-steps, LDS-staged x.
// Block = 256 thr (4 waves); wave w owns channel c0+w; 128 nodes/wave.
// Dual accumulators: acc <- bf0,bf2,bf4,bf6 ; acc2 <- bf1,bf3,bf5.
// ---------------------------------------------------------------------------

// R12's QSTEP with named H operands (identical arithmetic: scalar muls+PK2).
#define QSTEP8(BF, XQ, H0, H1, H2, H3, H4, H5, H6, H7, ACC)                    \
  __builtin_amdgcn_mfma_f32_16x16x32_bf16((BF),                                \
      __builtin_bit_cast(short8, (u32x4){                                      \
          PK2((XQ) * (H1), (XQ) * (H0)), PK2((XQ) * (H3), (XQ) * (H2)),        \
          PK2((XQ) * (H5), (XQ) * (H4)), PK2((XQ) * (H7), (XQ) * (H6))}),      \
      (ACC), 0, 0, 0)

#define TILE_BODY(X0, X1, X2, X3, VOUT)                                        \
  do {                                                                         \
    const float xh0 = ghi ? (X2).x : (X0).x;                                   \
    const float xh1 = ghi ? (X2).y : (X0).y;                                   \
    const float xh2 = ghi ? (X2).z : (X0).z;                                   \
    const float xh3 = ghi ? (X2).w : (X0).w;                                   \
    const float xh4 = ghi ? (X3).x : (X1).x;                                   \
    const float xh5 = ghi ? (X3).y : (X1).y;                                   \
    const float xh6 = ghi ? (X3).z : (X1).z;                                   \
    const float xh7 = ghi ? (X3).w : (X1).w;                                   \
    const float xq0 = gq ? (X0).y : (X0).x;                                    \
    const float xq1 = gq ? (X0).w : (X0).z;                                    \
    const float xq2 = gq ? (X1).y : (X1).x;                                    \
    const float xq3 = gq ? (X1).w : (X1).z;                                    \
    const float xq4 = (g == 0) ? (X2).x                                        \
                   : (g == 1) ? (X2).y                                         \
                   : (g == 2) ? (X2).z : (X2).w;      /* x[8+g]  */            \
    const float xq5 = (g == 0) ? (X3).x                                        \
                   : (g == 1) ? (X3).y                                         \
                   : (g == 2) ? (X3).z : (X3).w;      /* x[12+g] */            \
    f32x4 acc  = (f32x4){0.f, 0.f, 0.f, 0.f};                                  \
    f32x4 acc2 = (f32x4){0.f, 0.f, 0.f, 0.f};                                  \
    acc  = QSTEP8(bf0, xq0, xh0, xh1, xh2, xh3, xh4, xh5, xh6, xh7, acc);      \
    acc2 = QSTEP8(bf1, xq1, xh0, xh1, xh2, xh3, xh4, xh5, xh6, xh7, acc2);     \
    acc  = QSTEP8(bf2, xq2, xh0, xh1, xh2, xh3, xh4, xh5, xh6, xh7, acc);      \
    acc2 = QSTEP8(bf3, xq3, xh0, xh1, xh2, xh3, xh4, xh5, xh6, xh7, acc2);     \
    acc  = QSTEP8(bf4, xq4, (X2).x, (X2).y, (X2).z, (X2).w,                    \
                  (X3).x, (X3).y, (X3).z, (X3).w, acc);                        \
    acc2 = QSTEP8(bf5, xq5, (X2).x, (X2).y, (X2).z, (X2).w,                    \
                  (X3).x, (X3).y, (X3).z, (X3).w, acc2);                       \
    {                                                                          \
      const float y0 = glin ? xh0 : cst;                                       \
      const float y1 = glin ? xh1 : 0.f;                                       \
      const float y2 = glin ? xh2 : 0.f;                                       \
      const float y3 = glin ? xh3 : 0.f;                                       \
      const float y4 = glin ? xh4 : 0.f;                                       \
      const float y5 = glin ? xh5 : 0.f;                                       \
      const float y6 = glin ? xh6 : 0.f;                                       \
      const float y7 = glin ? xh7 : 0.f;                                       \
      acc = __builtin_amdgcn_mfma_f32_16x16x32_bf16(bf6,                       \
          __builtin_bit_cast(short8, (u32x4){PK2(y1, y0), PK2(y3, y2),         \
                                             PK2(y5, y4), PK2(y7, y6)}),       \
          acc, 0, 0, 0);                                                       \
    }                                                                          \
    acc = acc + acc2;                                                          \
    const float4 xs4 = (g & 2) ? ((g & 1) ? (X3) : (X2))                       \
                               : ((g & 1) ? (X1) : (X0));                      \
    float v = acc[0] * xs4.x + acc[1] * xs4.y + acc[2] * xs4.z + acc[3] * xs4.w;\
    v += __shfl_xor(v, 16);                                                    \
    v += __shfl_xor(v, 32);                                                    \
    (VOUT) = v;                                                                \
  } while (0)

// Tile T: wait for its staged 1KB (NREM = 7-T stages still allowed in
// flight; literal so the wait is exact), fence the scheduler (rule 18),
// swizzle-read the 4 float4 chunks, run the MFMA body.
#define TILE_AT(T, NREM, VOUT)                                                 \
  do {                                                                         \
    asm volatile("s_waitcnt vmcnt(" #NREM ")" ::: "memory");                   \
    __builtin_amdgcn_sched_barrier(0);                                         \
    const float* lw = lbase + (T) * 256;                                       \
    const float4 X0 = *(const float4*)(lw + n16 + sw0);                        \
    const float4 X1 = *(const float4*)(lw + n16 + sw1);                        \
    const float4 X2 = *(const float4*)(lw + n16 + sw2);                        \
    const float4 X3 = *(const float4*)(lw + n16 + sw3);                        \
    TILE_BODY(X0, X1, X2, X3, VOUT);                                           \
  } while (0)

__global__ __launch_bounds__(256)
__attribute__((amdgpu_waves_per_eu(2, 4)))
void contract_mfma(
    const float* __restrict__ x, const short8* __restrict__ bfragv,
    float* __restrict__ sT) {
  const int c0  = blockIdx.x * 4;                    // channel group (fastest)
  const int nb0 = blockIdx.y * (TILES_PER_WAVE * 16);
  const int t   = threadIdx.x;
  const int w = t >> 6, lane = t & 63, n = lane & 15, g = lane >> 4;
  const int ch = c0 + w;

  // x staging: 4 waves x 8 tiles x 1KB = 32KB/block.
  __shared__ float xstage[4][TILES_PER_WAVE][256];

  // Coeff fragments: 7 coalesced dwordx4 into NAMED registers (28 VGPRs).
  const short8* bp = bfragv + (size_t)ch * (KSTEPS * 64);
  const short8 bf0 = bp[0 * 64 + lane];
  const short8 bf1 = bp[1 * 64 + lane];
  const short8 bf2 = bp[2 * 64 + lane];
  const short8 bf3 = bp[3 * 64 + lane];
  const short8 bf4 = bp[4 * 64 + lane];
  const short8 bf5 = bp[5 * 64 + lane];
  const short8 bf6 = bp[6 * 64 + lane];

  const bool  ghi  = (g & 1) != 0;        // i-half: i = (g&1)*8 + j
  const bool  gq   = ((g >> 1) & 1) != 0; // steps 0..3: q = 2s + (g>>1)
  const bool  glin = (g < 2);             // step-6 linear rows live in g<2
  const float cst  = (g == 2) ? 1.0f : 0.0f;  // step-6 constant row
  float* sTrow = sT + (size_t)ch * B_NODES + nb0;

  // Stage addresses: lane l handles node nl=l>>2, 16B slot sl=l&3; the
  // GLOBAL chunk is pre-swizzled (cg = sl ^ ((nl>>1)&3)) so the linear LDS
  // write + swizzled read round-trips (rule 21, both sides).
  const int nl = lane >> 2;
  const int sl = lane & 3;
  const int cg = sl ^ ((nl >> 1) & 3);
  const size_t tstride = (size_t)16 * C_CH * 16;     // 16 nodes (floats)
  const float* gs = x + (size_t)(nb0 + nl) * (C_CH * 16) + (size_t)ch * 16
                      + (size_t)cg * 4;
  float* lbase = &xstage[w][0][0];
#pragma unroll
  for (int T = 0; T < TILES_PER_WAVE; ++T)
    stage16(gs + (size_t)T * tstride, lbase + T * 256);
  __builtin_amdgcn_sched_barrier(0);

  // Read-side swizzle constants (floats): chunk c lives at ((c^swz)<<2).
  const int n16 = n * 16;
  const int swz = (n >> 1) & 3;
  const int sw0 = (0 ^ swz) << 2;
  const int sw1 = (1 ^ swz) << 2;
  const int sw2 = (2 ^ swz) << 2;
  const int sw3 = (3 ^ swz) << 2;

  float v0, v1, v2, v3, v4, v5, v6, v7;
  TILE_AT(0, 7, v0);
  TILE_AT(1, 6, v1);
  TILE_AT(2, 5, v2);
  TILE_AT(3, 4, v3);
  TILE_AT(4, 3, v4);
  TILE_AT(5, 2, v5);
  TILE_AT(6, 1, v6);
  TILE_AT(7, 0, v7);

  if (g == 0) {
    sTrow[0 * 16 + n] = v0;
    sTrow[1 * 16 + n] = v1;
    sTrow[2 * 16 + n] = v2;
    sTrow[3 * 16 + n] = v3;
    sTrow[4 * 16 + n] = v4;
    sTrow[5 * 16 + n] = v5;
    sTrow[6 * 16 + n] = v6;
    sTrow[7 * 16 + n] = v7;
  }
}

// ---------------------------------------------------------------------------
// Kernel 3: out[b,d] = (1/16) * sum_c sT[c,b] * W[c,d]  (fp32, 64x64 tiles)
// (UNCHANGED from R15.)
// ---------------------------------------------------------------------------
__global__ __launch_bounds__(256) void linear_kernel(
    const float* __restrict__ sT, const float* __restrict__ W,
    float* __restrict__ out) {
  const int b0 = blockIdx.x * 64;
  const int d0 = blockIdx.y * 64;
  const int t  = threadIdx.x;
  const int tx = t & 15;
  const int ty = t >> 4;

  __shared__ float As[16][64];
  __shared__ float Bs[16][64];
  float acc[4][4] = {};

  for (int k0 = 0; k0 < C_CH; k0 += 16) {
    const int kk  = t >> 6;
    const int col = t & 63;
#pragma unroll
    for (int r = 0; r < 4; ++r) {
      As[kk + r * 4][col] = sT[(size_t)(k0 + kk + r * 4) * B_NODES + b0 + col];
      Bs[kk + r * 4][col] = W[(size_t)(k0 + kk + r * 4) * C_CH + d0 + col];
    }
    __syncthreads();
#pragma unroll
    for (int k = 0; k < 16; ++k) {
      float a[4], bv[4];
#pragma unroll
      for (int i = 0; i < 4; ++i) a[i] = As[k][ty * 4 + i];
#pragma unroll
      for (int j = 0; j < 4; ++j) bv[j] = Bs[k][tx * 4 + j];
#pragma unroll
      for (int i = 0; i < 4; ++i)
#pragma unroll
        for (int j = 0; j < 4; ++j) acc[i][j] += a[i] * bv[j];
    }
    __syncthreads();
  }

#pragma unroll
  for (int i = 0; i < 4; ++i) {
    float4 v = make_float4(acc[i][0] * 0.0625f, acc[i][1] * 0.0625f,
                           acc[i][2] * 0.0625f, acc[i][3] * 0.0625f);
    *(float4*)(out + (size_t)(b0 + ty * 4 + i) * C_CH + d0 + tx * 4) = v;
  }
}

extern "C" void kernel_launch(void* const* d_in, const int* in_sizes, int n_in,
                              void* d_out, int out_size, void* d_ws, size_t ws_size,
                              hipStream_t stream) {
  const float* x  = (const float*)d_in[0];
  const float* U3 = (const float*)d_in[1];
  const float* U2 = (const float*)d_in[2];
  const float* U1 = (const float*)d_in[3];
  const float* w3 = (const float*)d_in[4];
  const float* w2 = (const float*)d_in[5];
  const float* w1 = (const float*)d_in[6];
  const float* Wl = (const float*)d_in[7];

  unsigned int* bfrag = (unsigned int*)((char*)d_ws + OFF_BF_BYTES);
  float*        sT    = (float*)((char*)d_ws + OFF_ST_BYTES);
  float*        out   = (float*)d_out;

  precompute_bfrag<<<dim3(C_CH), dim3(256), 0, stream>>>(
      U3, U2, U1, w3, w2, w1, bfrag);
  contract_mfma<<<dim3(C_CH / 4, B_NODES / (TILES_PER_WAVE * 16)), dim3(256), 0, stream>>>(
      x, (const short8*)bfrag, sT);
  linear_kernel<<<dim3(B_NODES / 64, C_CH / 64), dim3(256), 0, stream>>>(sT, Wl, out);
}

// Round 7
// 129.002 us; speedup vs baseline: 1.1875x; 1.0744x over previous
//
#include <hip/hip_runtime.h>

// MACE symmetric contraction, B=4096 nodes, C=256 channels, I=16.
//
// Per (b,c):  s[b,c] = sum_p x_p * t[b,p],
//   t[b,p] = sum_{q<=i} Af[c,p,q,i]*x_q*x_i    (symmetric fold of U3w)
//          + sum_i c2[c,p,i]*x_i  +  c1[c,p]
// Af[p,q,i] = U3w[p,q,i]+U3w[p,i,q] (q<i), U3w[p,q,q] (q=i), 0 (q>i).
// 7 MFMA K-steps of 32; contract x staged via 8-deep global_load_lds
// pipeline with counted vmcnt (R16, PASSED 138.6us; -12.7 matched the
// latency-bound prediction).
//
// R18 = R16 + linear_kernel -> bf16 MFMA (kernels 1,2 byte-identical).
// linear is a 4096x256x256 GEMM; fp32-vector version ~5-6us vs ~1.4us mem
// floor. Fragment layouts (A row=lane&15, k=(lane>>4)*8+j; B col=lane&15;
// D col=lane&15, row=(lane>>4)*4+r) are all verified by the passing
// contract kernel. Each wave = one 16b x 16d tile, 8 K-steps over c.
// sT/W packed to bf16 with RNE (accuracy: adds ~1 sigma to absmax; 8.0
// measured vs 39.36 threshold leaves room).
//
// Kept: dual accumulators, zero allocas, ~110 live-reg ceiling (R11),
// vmcnt ladder interleave-proof (7 bfrag + 8 stages; tile T waits 7-T).
// Harness floor: ws-poison fill ~41us + d_in restore ~25us + misc => ~110us
// of dur_us is uncontrollable.

#define B_NODES 4096
#define C_CH    256
#define K3      23
#define K2      4

#define KSTEPS   7
#define KB_ELEMS (KSTEPS * 64 * 8)   // 3584 bf16 per channel
#define KB_U32   (KB_ELEMS / 2)      // 1792 u32 per channel

#define TILES_PER_WAVE 8             // 128 nodes per wave

typedef short    short8 __attribute__((ext_vector_type(8)));
typedef float    f32x4  __attribute__((ext_vector_type(4)));
typedef unsigned u32x4  __attribute__((ext_vector_type(4)));

// ws layout (bytes): [bfrag: C*3584*2][sT: C*B*4]
static constexpr size_t OFF_BF_BYTES = 0;
static constexpr size_t OFF_ST_BYTES = (size_t)C_CH * KB_ELEMS * 2;

__device__ inline unsigned short f2bf_rne(float f) {
  unsigned u = __builtin_bit_cast(unsigned, f);
  unsigned r = u + 0x7FFFu + ((u >> 16) & 1u);
  return (unsigned short)(r >> 16);
}

#define F2U(f) __builtin_bit_cast(unsigned, (f))
// pack two f32 (truncate-to-bf16 high halves) into one u32: [hi16(YH)|hi16(YL)]
#define PK2(YH, YL) __builtin_amdgcn_perm(F2U(YH), F2U(YL), 0x07060302u)

// RNE variant for the linear GEMM (lo -> bits 0..15, hi -> bits 16..31).
__device__ __forceinline__ unsigned pk_rne(float hi, float lo) {
  return (unsigned)f2bf_rne(lo) | ((unsigned)f2bf_rne(hi) << 16);
}

// async global->LDS, 16B/lane; LDS dest = wave-uniform base + lane*16.
__device__ __forceinline__ void stage16(const float* g, float* l) {
  __builtin_amdgcn_global_load_lds(
      (const __attribute__((address_space(1))) unsigned int*)g,
      (__attribute__((address_space(3))) unsigned int*)l, 16, 0, 0);
}

// ---------------------------------------------------------------------------
// Kernel 1: folded coeffs, 7-step layout (lane&15 = p, slot j = 2*(t&3)+e).
// One block per channel; U3w staged in 16KB LDS; fold applied in f32
// before bf16 quantization. Triangle zeros (q>i) baked into coefficients.
// (UNCHANGED from R16.)
// ---------------------------------------------------------------------------
__global__ __launch_bounds__(256) void precompute_bfrag(
    const float* __restrict__ U3, const float* __restrict__ U2,
    const float* __restrict__ U1, const float* __restrict__ w3,
    const float* __restrict__ w2, const float* __restrict__ w1,
    unsigned int* __restrict__ bfrag_u32) {
  const int c = blockIdx.x;
  const int t = threadIdx.x;

  __shared__ float su3w[4096];       // [p][q][i], this channel's U3w
  for (int l = t; l < 4096; l += 256) {
    float a = 0.f;
#pragma unroll
    for (int k3 = 0; k3 < K3; ++k3)
      a += U3[(size_t)l * K3 + k3] * w3[c * K3 + k3];   // w3: uniform scalar
    su3w[l] = a;
  }
  __syncthreads();

  const int lane = t >> 2;           // fragment lane
  const int jj   = (t & 3) * 2;      // 0,2,4,6
  const int p = lane & 15, g = lane >> 4;

  // steps 0..3: quadratic, low-q, old map.
#pragma unroll
  for (int s = 0; s < 4; ++s) {
    const int q = 2 * s + (g >> 1);
    float v0 = 0.f, v1 = 0.f;
#pragma unroll
    for (int e = 0; e < 2; ++e) {
      const int i = (g & 1) * 8 + jj + e;
      float a = 0.f;
      if (q < i)
        a = su3w[(p * 16 + q) * 16 + i] + su3w[(p * 16 + i) * 16 + q];
      else if (q == i)
        a = su3w[(p * 16 + q) * 16 + q];
      if (e == 0) v0 = a; else v1 = a;
    }
    bfrag_u32[(size_t)c * KB_U32 + s * 256 + t] =
        (unsigned)f2bf_rne(v0) | ((unsigned)f2bf_rne(v1) << 16);
  }

  // steps 4..5: quadratic, high-q compacted: q = 8+(s-4)*4+g, i = 8+j.
#pragma unroll
  for (int s = 4; s < 6; ++s) {
    const int q = 8 + (s - 4) * 4 + g;
    float v0 = 0.f, v1 = 0.f;
#pragma unroll
    for (int e = 0; e < 2; ++e) {
      const int i = 8 + jj + e;
      float a = 0.f;
      if (q < i)
        a = su3w[(p * 16 + q) * 16 + i] + su3w[(p * 16 + i) * 16 + q];
      else if (q == i)
        a = su3w[(p * 16 + q) * 16 + q];
      if (e == 0) v0 = a; else v1 = a;
    }
    bfrag_u32[(size_t)c * KB_U32 + s * 256 + t] =
        (unsigned)f2bf_rne(v0) | ((unsigned)f2bf_rne(v1) << 16);
  }

  // step 6: linear rows (x_i), constant row, pad 0.
  {
    float v0 = 0.f, v1 = 0.f;
#pragma unroll
    for (int e = 0; e < 2; ++e) {
      const int k = 256 + g * 8 + jj + e;
      float a = 0.f;
      if (k < 272) {
        const int q = k - 256;
#pragma unroll
        for (int k2 = 0; k2 < K2; ++k2)
          a += U2[(size_t)(p * 16 + q) * K2 + k2] * w2[c * K2 + k2];
      } else if (k == 272) {
        a = U1[p] * w1[c];
      }
      if (e == 0) v0 = a; else v1 = a;
    }
    bfrag_u32[(size_t)c * KB_U32 + 6 * 256 + t] =
        (unsigned)f2bf_rne(v0) | ((unsigned)f2bf_rne(v1) << 16);
  }
}

// ---------------------------------------------------------------------------
// Kernel 2: wave-autonomous MFMA contraction, 7 K-steps, LDS-staged x.
// Block = 256 thr (4 waves); wave w owns channel c0+w; 128 nodes/wave.
// Dual accumulators: acc <- bf0,bf2,bf4,bf6 ; acc2 <- bf1,bf3,bf5.
// (UNCHANGED from R16.)
// ---------------------------------------------------------------------------

// R12's QSTEP with named H operands (identical arithmetic: scalar muls+PK2).
#define QSTEP8(BF, XQ, H0, H1, H2, H3, H4, H5, H6, H7, ACC)                    \
  __builtin_amdgcn_mfma_f32_16x16x32_bf16((BF),                                \
      __builtin_bit_cast(short8, (u32x4){                                      \
          PK2((XQ) * (H1), (XQ) * (H0)), PK2((XQ) * (H3), (XQ) * (H2)),        \
          PK2((XQ) * (H5), (XQ) * (H4)), PK2((XQ) * (H7), (XQ) * (H6))}),      \
      (ACC), 0, 0, 0)

#define TILE_BODY(X0, X1, X2, X3, VOUT)                                        \
  do {                                                                         \
    const float xh0 = ghi ? (X2).x : (X0).x;                                   \
    const float xh1 = ghi ? (X2).y : (X0).y;                                   \
    const float xh2 = ghi ? (X2).z : (X0).z;                                   \
    const float xh3 = ghi ? (X2).w : (X0).w;                                   \
    const float xh4 = ghi ? (X3).x : (X1).x;                                   \
    const float xh5 = ghi ? (X3).y : (X1).y;                                   \
    const float xh6 = ghi ? (X3).z : (X1).z;                                   \
    const float xh7 = ghi ? (X3).w : (X1).w;                                   \
    const float xq0 = gq ? (X0).y : (X0).x;                                    \
    const float xq1 = gq ? (X0).w : (X0).z;                                    \
    const float xq2 = gq ? (X1).y : (X1).x;                                    \
    const float xq3 = gq ? (X1).w : (X1).z;                                    \
    const float xq4 = (g == 0) ? (X2).x                                        \
                   : (g == 1) ? (X2).y                                         \
                   : (g == 2) ? (X2).z : (X2).w;      /* x[8+g]  */            \
    const float xq5 = (g == 0) ? (X3).x                                        \
                   : (g == 1) ? (X3).y                                         \
                   : (g == 2) ? (X3).z : (X3).w;      /* x[12+g] */            \
    f32x4 acc  = (f32x4){0.f, 0.f, 0.f, 0.f};                                  \
    f32x4 acc2 = (f32x4){0.f, 0.f, 0.f, 0.f};                                  \
    acc  = QSTEP8(bf0, xq0, xh0, xh1, xh2, xh3, xh4, xh5, xh6, xh7, acc);      \
    acc2 = QSTEP8(bf1, xq1, xh0, xh1, xh2, xh3, xh4, xh5, xh6, xh7, acc2);     \
    acc  = QSTEP8(bf2, xq2, xh0, xh1, xh2, xh3, xh4, xh5, xh6, xh7, acc);      \
    acc2 = QSTEP8(bf3, xq3, xh0, xh1, xh2, xh3, xh4, xh5, xh6, xh7, acc2);     \
    acc  = QSTEP8(bf4, xq4, (X2).x, (X2).y, (X2).z, (X2).w,                    \
                  (X3).x, (X3).y, (X3).z, (X3).w, acc);                        \
    acc2 = QSTEP8(bf5, xq5, (X2).x, (X2).y, (X2).z, (X2).w,                    \
                  (X3).x, (X3).y, (X3).z, (X3).w, acc2);                       \
    {                                                                          \
      const float y0 = glin ? xh0 : cst;                                       \
      const float y1 = glin ? xh1 : 0.f;                                       \
      const float y2 = glin ? xh2 : 0.f;                                       \
      const float y3 = glin ? xh3 : 0.f;                                       \
      const float y4 = glin ? xh4 : 0.f;                                       \
      const float y5 = glin ? xh5 : 0.f;                                       \
      const float y6 = glin ? xh6 : 0.f;                                       \
      const float y7 = glin ? xh7 : 0.f;                                       \
      acc = __builtin_amdgcn_mfma_f32_16x16x32_bf16(bf6,                       \
          __builtin_bit_cast(short8, (u32x4){PK2(y1, y0), PK2(y3, y2),         \
                                             PK2(y5, y4), PK2(y7, y6)}),       \
          acc, 0, 0, 0);                                                       \
    }                                                                          \
    acc = acc + acc2;                                                          \
    const float4 xs4 = (g & 2) ? ((g & 1) ? (X3) : (X2))                       \
                               : ((g & 1) ? (X1) : (X0));                      \
    float v = acc[0] * xs4.x + acc[1] * xs4.y + acc[2] * xs4.z + acc[3] * xs4.w;\
    v += __shfl_xor(v, 16);                                                    \
    v += __shfl_xor(v, 32);                                                    \
    (VOUT) = v;                                                                \
  } while (0)

// Tile T: wait for its staged 1KB (NREM = 7-T stages still allowed in
// flight; literal so the wait is exact), fence the scheduler (rule 18),
// swizzle-read the 4 float4 chunks, run the MFMA body.
#define TILE_AT(T, NREM, VOUT)                                                 \
  do {                                                                         \
    asm volatile("s_waitcnt vmcnt(" #NREM ")" ::: "memory");                   \
    __builtin_amdgcn_sched_barrier(0);                                         \
    const float* lw = lbase + (T) * 256;                                       \
    const float4 X0 = *(const float4*)(lw + n16 + sw0);                        \
    const float4 X1 = *(const float4*)(lw + n16 + sw1);                        \
    const float4 X2 = *(const float4*)(lw + n16 + sw2);                        \
    const float4 X3 = *(const float4*)(lw + n16 + sw3);                        \
    TILE_BODY(X0, X1, X2, X3, VOUT);                                           \
  } while (0)

__global__ __launch_bounds__(256)
__attribute__((amdgpu_waves_per_eu(2, 4)))
void contract_mfma(
    const float* __restrict__ x, const short8* __restrict__ bfragv,
    float* __restrict__ sT) {
  const int c0  = blockIdx.x * 4;                    // channel group (fastest)
  const int nb0 = blockIdx.y * (TILES_PER_WAVE * 16);
  const int t   = threadIdx.x;
  const int w = t >> 6, lane = t & 63, n = lane & 15, g = lane >> 4;
  const int ch = c0 + w;

  // x staging: 4 waves x 8 tiles x 1KB = 32KB/block.
  __shared__ float xstage[4][TILES_PER_WAVE][256];

  // Coeff fragments: 7 coalesced dwordx4 into NAMED registers (28 VGPRs).
  const short8* bp = bfragv + (size_t)ch * (KSTEPS * 64);
  const short8 bf0 = bp[0 * 64 + lane];
  const short8 bf1 = bp[1 * 64 + lane];
  const short8 bf2 = bp[2 * 64 + lane];
  const short8 bf3 = bp[3 * 64 + lane];
  const short8 bf4 = bp[4 * 64 + lane];
  const short8 bf5 = bp[5 * 64 + lane];
  const short8 bf6 = bp[6 * 64 + lane];

  const bool  ghi  = (g & 1) != 0;        // i-half: i = (g&1)*8 + j
  const bool  gq   = ((g >> 1) & 1) != 0; // steps 0..3: q = 2s + (g>>1)
  const bool  glin = (g < 2);             // step-6 linear rows live in g<2
  const float cst  = (g == 2) ? 1.0f : 0.0f;  // step-6 constant row
  float* sTrow = sT + (size_t)ch * B_NODES + nb0;

  // Stage addresses: lane l handles node nl=l>>2, 16B slot sl=l&3; the
  // GLOBAL chunk is pre-swizzled (cg = sl ^ ((nl>>1)&3)) so the linear LDS
  // write + swizzled read round-trips (rule 21, both sides).
  const int nl = lane >> 2;
  const int sl = lane & 3;
  const int cg = sl ^ ((nl >> 1) & 3);
  const size_t tstride = (size_t)16 * C_CH * 16;     // 16 nodes (floats)
  const float* gs = x + (size_t)(nb0 + nl) * (C_CH * 16) + (size_t)ch * 16
                      + (size_t)cg * 4;
  float* lbase = &xstage[w][0][0];
#pragma unroll
  for (int T = 0; T < TILES_PER_WAVE; ++T)
    stage16(gs + (size_t)T * tstride, lbase + T * 256);
  __builtin_amdgcn_sched_barrier(0);

  // Read-side swizzle constants (floats): chunk c lives at ((c^swz)<<2).
  const int n16 = n * 16;
  const int swz = (n >> 1) & 3;
  const int sw0 = (0 ^ swz) << 2;
  const int sw1 = (1 ^ swz) << 2;
  const int sw2 = (2 ^ swz) << 2;
  const int sw3 = (3 ^ swz) << 2;

  float v0, v1, v2, v3, v4, v5, v6, v7;
  TILE_AT(0, 7, v0);
  TILE_AT(1, 6, v1);
  TILE_AT(2, 5, v2);
  TILE_AT(3, 4, v3);
  TILE_AT(4, 3, v4);
  TILE_AT(5, 2, v5);
  TILE_AT(6, 1, v6);
  TILE_AT(7, 0, v7);

  if (g == 0) {
    sTrow[0 * 16 + n] = v0;
    sTrow[1 * 16 + n] = v1;
    sTrow[2 * 16 + n] = v2;
    sTrow[3 * 16 + n] = v3;
    sTrow[4 * 16 + n] = v4;
    sTrow[5 * 16 + n] = v5;
    sTrow[6 * 16 + n] = v6;
    sTrow[7 * 16 + n] = v7;
  }
}

// ---------------------------------------------------------------------------
// Kernel 3 (NEW): out[b,d] = (1/16) * sum_c sT[c,b] * W[c,d] via bf16 MFMA.
// One wave per 16b x 16d out-tile; 8 K-steps of 32 channels. Fragment maps
// proven by the contract kernel: A row=lane&15 (b), k=(lane>>4)*8+j;
// B col=lane&15 (d), same k; D col=lane&15 (d), row=(lane>>4)*4+r (b).
// sT (c-major) loads: per (g,j) 16 consecutive b floats -> 64B runs.
// W is 256KB, L2-hot. RNE packing keeps added quantization ~1 sigma.
// ---------------------------------------------------------------------------
__global__ __launch_bounds__(256) void linear_mfma(
    const float* __restrict__ sT, const float* __restrict__ W,
    float* __restrict__ out) {
  const int t = threadIdx.x;
  const int w = t >> 6, lane = t & 63, n = lane & 15, g = lane >> 4;
  const int b0 = (blockIdx.x * 4 + w) * 16;
  const int d0 = blockIdx.y * 16;

  // Base pointers for this lane's fragment rows (k = g*8 + j).
  const float* sa = sT + (size_t)(g * 8) * B_NODES + b0 + n;
  const float* wb = W  + (size_t)(g * 8) * C_CH   + d0 + n;

  f32x4 acc = (f32x4){0.f, 0.f, 0.f, 0.f};
#pragma unroll 2
  for (int ks = 0; ks < 8; ++ks) {
    const size_t ca = (size_t)ks * 32 * B_NODES;
    const size_t cb = (size_t)ks * 32 * C_CH;
    const float a0 = sa[ca + 0 * B_NODES], a1 = sa[ca + 1 * B_NODES];
    const float a2 = sa[ca + 2 * B_NODES], a3 = sa[ca + 3 * B_NODES];
    const float a4 = sa[ca + 4 * B_NODES], a5 = sa[ca + 5 * B_NODES];
    const float a6 = sa[ca + 6 * B_NODES], a7 = sa[ca + 7 * B_NODES];
    const float q0 = wb[cb + 0 * C_CH], q1 = wb[cb + 1 * C_CH];
    const float q2 = wb[cb + 2 * C_CH], q3 = wb[cb + 3 * C_CH];
    const float q4 = wb[cb + 4 * C_CH], q5 = wb[cb + 5 * C_CH];
    const float q6 = wb[cb + 6 * C_CH], q7 = wb[cb + 7 * C_CH];
    const u32x4 af = (u32x4){pk_rne(a1, a0), pk_rne(a3, a2),
                             pk_rne(a5, a4), pk_rne(a7, a6)};
    const u32x4 bfv = (u32x4){pk_rne(q1, q0), pk_rne(q3, q2),
                              pk_rne(q5, q4), pk_rne(q7, q6)};
    acc = __builtin_amdgcn_mfma_f32_16x16x32_bf16(
        __builtin_bit_cast(short8, af), __builtin_bit_cast(short8, bfv),
        acc, 0, 0, 0);
  }

  // D: col = n (d), row = g*4 + r (b); scale by 1/16.
#pragma unroll
  for (int r = 0; r < 4; ++r)
    out[(size_t)(b0 + g * 4 + r) * C_CH + d0 + n] = acc[r] * 0.0625f;
}

extern "C" void kernel_launch(void* const* d_in, const int* in_sizes, int n_in,
                              void* d_out, int out_size, void* d_ws, size_t ws_size,
                              hipStream_t stream) {
  const float* x  = (const float*)d_in[0];
  const float* U3 = (const float*)d_in[1];
  const float* U2 = (const float*)d_in[2];
  const float* U1 = (const float*)d_in[3];
  const float* w3 = (const float*)d_in[4];
  const float* w2 = (const float*)d_in[5];
  const float* w1 = (const float*)d_in[6];
  const float* Wl = (const float*)d_in[7];

  unsigned int* bfrag = (unsigned int*)((char*)d_ws + OFF_BF_BYTES);
  float*        sT    = (float*)((char*)d_ws + OFF_ST_BYTES);
  float*        out   = (float*)d_out;

  precompute_bfrag<<<dim3(C_CH), dim3(256), 0, stream>>>(
      U3, U2, U1, w3, w2, w1, bfrag);
  contract_mfma<<<dim3(C_CH / 4, B_NODES / (TILES_PER_WAVE * 16)), dim3(256), 0, stream>>>(
      x, (const short8*)bfrag, sT);
  linear_mfma<<<dim3(B_NODES / 64, C_CH / 16), dim3(256), 0, stream>>>(sT, Wl, out);
}